// Round 5
// baseline (576.820 us; speedup 1.0000x reference)
//
#include <hip/hip_runtime.h>

#define F_IN 512
#define H1   8
#define D1   8
#define C1   64   // H1*D1
#define C2   40

__device__ __forceinline__ float leaky02(float x) { return x > 0.f ? x : 0.2f * x; }

// ---------------------------------------------------------------------------
// GEMM1 v3: h1 = x @ W1 (N x 512)@(512 x 64), fused alpha epilogue.
// Tile 64 nodes x 64 cols, BK=32; per-thread 4x4 register tile.
// Register double-buffer: issue next chunk's global loads BEFORE compute,
// LDS-write AFTER (hides HBM latency under FMA phase). Grid 1563 (~6/CU).
// ---------------------------------------------------------------------------
__global__ __launch_bounds__(256, 6) void gemm1_kernel(
    const float* __restrict__ x, const float* __restrict__ W1,
    const float* __restrict__ a_src, const float* __restrict__ a_dst,
    float* __restrict__ h1, float* __restrict__ as1, float* __restrict__ ad1,
    int N)
{
    __shared__ float xsT[32][68];   // 8.7 KB transposed x chunk (+4 pad)
    __shared__ float Ws[32][64];    // 8 KB
    const int tid = threadIdx.x;
    const int cg  = tid & 15;       // cols cg*4..cg*4+3
    const int ng  = tid >> 4;       // nodes ng*4..ng*4+3
    const int n0  = blockIdx.x * 64;

    // staging index maps (2 float4 each for x and W per thread)
    const int xnl0 = tid >> 3, xq0 = tid & 7;             // idx = tid
    const int xnl1 = (tid + 256) >> 3, xq1 = tid & 7;     // idx = tid+256
    const int wrow0 = tid >> 4, wc0 = tid & 15;
    const int wrow1 = (tid + 256) >> 4, wc1 = tid & 15;

    float a_s[4], a_d[4];
    #pragma unroll
    for (int j = 0; j < 4; ++j) { a_s[j] = a_src[cg * 4 + j]; a_d[j] = a_dst[cg * 4 + j]; }

    float acc[4][4];
    #pragma unroll
    for (int i = 0; i < 4; ++i)
        #pragma unroll
        for (int j = 0; j < 4; ++j) acc[i][j] = 0.f;

    float4 xr0, xr1, wr0, wr1;
    auto load_chunk = [&](int kb) {
        int na = n0 + xnl0; if (na > N - 1) na = N - 1;
        int nb = n0 + xnl1; if (nb > N - 1) nb = N - 1;
        xr0 = *(const float4*)&x[(size_t)na * F_IN + kb + xq0 * 4];
        xr1 = *(const float4*)&x[(size_t)nb * F_IN + kb + xq1 * 4];
        wr0 = *(const float4*)&W1[(size_t)(kb + wrow0) * C1 + wc0 * 4];
        wr1 = *(const float4*)&W1[(size_t)(kb + wrow1) * C1 + wc1 * 4];
    };
    auto write_chunk = [&]() {
        xsT[xq0 * 4 + 0][xnl0] = xr0.x; xsT[xq0 * 4 + 1][xnl0] = xr0.y;
        xsT[xq0 * 4 + 2][xnl0] = xr0.z; xsT[xq0 * 4 + 3][xnl0] = xr0.w;
        xsT[xq1 * 4 + 0][xnl1] = xr1.x; xsT[xq1 * 4 + 1][xnl1] = xr1.y;
        xsT[xq1 * 4 + 2][xnl1] = xr1.z; xsT[xq1 * 4 + 3][xnl1] = xr1.w;
        *(float4*)&Ws[wrow0][wc0 * 4] = wr0;
        *(float4*)&Ws[wrow1][wc1 * 4] = wr1;
    };

    load_chunk(0);
    write_chunk();
    __syncthreads();

    for (int kb = 32; kb <= F_IN; kb += 32) {
        if (kb < F_IN) load_chunk(kb);   // in-flight during compute
        #pragma unroll 8
        for (int kk = 0; kk < 32; ++kk) {
            float4 xa = *(float4*)&xsT[kk][ng * 4];
            float4 wv = *(float4*)&Ws[kk][cg * 4];
            const float xv[4] = {xa.x, xa.y, xa.z, xa.w};
            const float wj[4] = {wv.x, wv.y, wv.z, wv.w};
            #pragma unroll
            for (int i = 0; i < 4; ++i)
                #pragma unroll
                for (int j = 0; j < 4; ++j)
                    acc[i][j] += xv[i] * wj[j];
        }
        __syncthreads();
        if (kb < F_IN) {
            write_chunk();
            __syncthreads();
        }
    }

    #pragma unroll
    for (int i = 0; i < 4; ++i) {
        const int n = n0 + ng * 4 + i;
        float s = acc[i][0] * a_s[0] + acc[i][1] * a_s[1]
                + acc[i][2] * a_s[2] + acc[i][3] * a_s[3];
        float d = acc[i][0] * a_d[0] + acc[i][1] * a_d[1]
                + acc[i][2] * a_d[2] + acc[i][3] * a_d[3];
        s += __shfl_xor(s, 1);
        d += __shfl_xor(d, 1);
        if (n < N) {
            *(float4*)&h1[(size_t)n * C1 + cg * 4] =
                make_float4(acc[i][0], acc[i][1], acc[i][2], acc[i][3]);
            if (!(cg & 1)) {
                as1[n * H1 + (cg >> 1)] = s;
                ad1[n * H1 + (cg >> 1)] = d;
            }
        }
    }
}

// ---------------------------------------------------------------------------
// CSR build: count -> scan(3 kernels) -> scatter.
// ---------------------------------------------------------------------------
__global__ __launch_bounds__(256) void count_kernel(
    const int* __restrict__ ei, int* __restrict__ deg, int E)
{
    int e = blockIdx.x * 256 + threadIdx.x;
    if (e >= E) return;
    atomicAdd(&deg[ei[E + e]], 1);
}

__global__ __launch_bounds__(512) void scan1_kernel(
    const int* __restrict__ deg, int* __restrict__ excl,
    int* __restrict__ bsum, int N)
{
    __shared__ int sA[512], sB[512];
    const int t = threadIdx.x;
    const int i = blockIdx.x * 512 + t;
    int v = (i < N) ? deg[i] : 0;
    sA[t] = v; __syncthreads();
    int* pin = sA; int* pout = sB;
    #pragma unroll
    for (int off = 1; off < 512; off <<= 1) {
        pout[t] = pin[t] + ((t >= off) ? pin[t - off] : 0);
        __syncthreads();
        int* tmp = pin; pin = pout; pout = tmp;
    }
    if (i < N) excl[i] = pin[t] - v;
    if (t == 511) bsum[blockIdx.x] = pin[511];
}

__global__ __launch_bounds__(256) void scan2_kernel(
    int* __restrict__ bsum, int* __restrict__ bsumo, int NB)
{
    __shared__ int sA[256], sB[256];
    const int t = threadIdx.x;
    int v = (t < NB) ? bsum[t] : 0;
    sA[t] = v; __syncthreads();
    int* pin = sA; int* pout = sB;
    #pragma unroll
    for (int off = 1; off < 256; off <<= 1) {
        pout[t] = pin[t] + ((t >= off) ? pin[t - off] : 0);
        __syncthreads();
        int* tmp = pin; pin = pout; pout = tmp;
    }
    if (t < NB) bsumo[t] = pin[t] - v;
}

__global__ __launch_bounds__(512) void scan3_kernel(
    const int* __restrict__ excl, const int* __restrict__ bsumo,
    int* __restrict__ rowptr, int* __restrict__ cursor, int N, int E)
{
    const int i = blockIdx.x * 512 + threadIdx.x;
    if (i < N) {
        int r = excl[i] + bsumo[blockIdx.x];
        rowptr[i] = r;
        cursor[i] = r;
    }
    if (i == 0) rowptr[N] = E;
}

__global__ __launch_bounds__(256) void scatter_kernel(
    const int* __restrict__ ei, int* __restrict__ cursor,
    int* __restrict__ esrc, int E)
{
    int e = blockIdx.x * 256 + threadIdx.x;
    if (e >= E) return;
    int src = ei[e], dst = ei[E + e];
    int pos = atomicAdd(&cursor[dst], 1);
    esrc[pos] = src;
}

// ---------------------------------------------------------------------------
// Layer-1 aggregation + finish, fused. One wave per dst node.
// 8-edge software pipeline.
// ---------------------------------------------------------------------------
__global__ __launch_bounds__(256) void agg1_kernel(
    const int* __restrict__ rowptr, const int* __restrict__ esrc,
    const float* __restrict__ h1, const float* __restrict__ as1,
    const float* __restrict__ ad1, const float* __restrict__ b1,
    float* __restrict__ h1f, int N)
{
    const int n = blockIdx.x * 4 + (threadIdx.x >> 6);
    if (n >= N) return;
    const int lane = threadIdx.x & 63;
    const int h = lane >> 3;
    const float adh = ad1[n * H1 + h];

    float acc = 0.f, den = 0.f;
    int i = rowptr[n];
    const int end = rowptr[n + 1];
    for (; i + 8 <= end; i += 8) {
        int s[8]; float v[8], a[8];
        #pragma unroll
        for (int u = 0; u < 8; ++u) s[u] = esrc[i + u];
        #pragma unroll
        for (int u = 0; u < 8; ++u) v[u] = h1[(size_t)s[u] * C1 + lane];
        #pragma unroll
        for (int u = 0; u < 8; ++u) a[u] = as1[s[u] * H1 + h];
        #pragma unroll
        for (int u = 0; u < 8; ++u) {
            const float ex = __expf(leaky02(a[u] + adh));
            acc += ex * v[u];
            den += ex;
        }
    }
    for (; i < end; ++i) {
        const int src = esrc[i];
        const float v  = h1[(size_t)src * C1 + lane];
        const float ex = __expf(leaky02(as1[src * H1 + h] + adh));
        acc += ex * v;
        den += ex;
    }
    {   // self loop
        const float ex = __expf(leaky02(as1[n * H1 + h] + adh));
        acc += ex * h1[(size_t)n * C1 + lane];
        den += ex;
    }
    float v = acc / den + b1[lane];
    h1f[(size_t)n * C1 + lane] = v > 0.f ? v : __expf(v) - 1.f;   // ELU
}

// ---------------------------------------------------------------------------
// GEMM2: h2 = h1f @ W2  (N x 64) @ (64 x 40), fused alpha2 epilogue.
// ---------------------------------------------------------------------------
__global__ __launch_bounds__(320) void gemm2_kernel(
    const float* __restrict__ h1f, const float* __restrict__ W2,
    const float* __restrict__ a_src2, const float* __restrict__ a_dst2,
    float* __restrict__ h2, float* __restrict__ as2, float* __restrict__ ad2,
    int N)
{
    __shared__ float hs[8][C1];
    __shared__ float W2s[C1 * C2];
    __shared__ float redS[8][C2], redD[8][C2];
    const int tid = threadIdx.x;
    const int n0  = blockIdx.x * 8;
    for (int i = tid; i < 8 * C1; i += 320) hs[i >> 6][i & 63] = h1f[(size_t)n0 * C1 + i];
    for (int i = tid; i < C1 * C2; i += 320) W2s[i] = W2[i];
    __syncthreads();
    const int g = tid / C2, c = tid % C2;
    float acc = 0.f;
    #pragma unroll
    for (int k = 0; k < C1; ++k) acc += hs[g][k] * W2s[k * C2 + c];
    const int n = n0 + g;
    h2[(size_t)n * C2 + c] = acc;
    redS[g][c] = acc * a_src2[c];
    redD[g][c] = acc * a_dst2[c];
    __syncthreads();
    if (c == 0) {
        float s = 0.f, d = 0.f;
        for (int j = 0; j < C2; ++j) { s += redS[g][j]; d += redD[g][j]; }
        as2[n] = s; ad2[n] = d;
    }
}

// ---------------------------------------------------------------------------
// Layer-2 aggregation + finish + log_softmax, fused. 8-edge pipeline.
// ---------------------------------------------------------------------------
__global__ __launch_bounds__(256) void agg2_kernel(
    const int* __restrict__ rowptr, const int* __restrict__ esrc,
    const float* __restrict__ h2, const float* __restrict__ as2,
    const float* __restrict__ ad2, const float* __restrict__ b2,
    float* __restrict__ out, int N)
{
    const int n = blockIdx.x * 4 + (threadIdx.x >> 6);
    if (n >= N) return;
    const int lane = threadIdx.x & 63;
    const float adn = ad2[n];

    float acc = 0.f, den = 0.f;
    int i = rowptr[n];
    const int end = rowptr[n + 1];
    for (; i + 8 <= end; i += 8) {
        int s[8]; float v[8], a[8];
        #pragma unroll
        for (int u = 0; u < 8; ++u) s[u] = esrc[i + u];
        #pragma unroll
        for (int u = 0; u < 8; ++u)
            v[u] = (lane < C2) ? h2[(size_t)s[u] * C2 + lane] : 0.f;
        #pragma unroll
        for (int u = 0; u < 8; ++u) a[u] = as2[s[u]];
        #pragma unroll
        for (int u = 0; u < 8; ++u) {
            const float ex = __expf(leaky02(a[u] + adn));
            acc += ex * v[u];
            den += ex;
        }
    }
    for (; i < end; ++i) {
        const int src = esrc[i];
        float v = (lane < C2) ? h2[(size_t)src * C2 + lane] : 0.f;
        const float ex = __expf(leaky02(as2[src] + adn));
        acc += ex * v;
        den += ex;
    }
    {   // self loop
        const float ex = __expf(leaky02(as2[n] + adn));
        if (lane < C2) acc += ex * h2[(size_t)n * C2 + lane];
        den += ex;
    }
    float v = (lane < C2) ? (acc / den + b2[lane]) : -1e30f;
    float m = v;
    #pragma unroll
    for (int s = 1; s < 64; s <<= 1) m = fmaxf(m, __shfl_xor(m, s));
    float e2x = (lane < C2) ? __expf(v - m) : 0.f;
    #pragma unroll
    for (int s = 1; s < 64; s <<= 1) e2x += __shfl_xor(e2x, s);
    float lse = __logf(e2x);
    if (lane < C2) out[(size_t)n * C2 + lane] = v - m - lse;
}

// ---------------------------------------------------------------------------
extern "C" void kernel_launch(void* const* d_in, const int* in_sizes, int n_in,
                              void* d_out, int out_size, void* d_ws, size_t ws_size,
                              hipStream_t stream)
{
    const float* x    = (const float*)d_in[0];
    const int*   ei   = (const int*)  d_in[1];
    const float* W1   = (const float*)d_in[2];
    const float* as1w = (const float*)d_in[3];
    const float* ad1w = (const float*)d_in[4];
    const float* b1   = (const float*)d_in[5];
    const float* W2   = (const float*)d_in[6];
    const float* as2w = (const float*)d_in[7];
    const float* ad2w = (const float*)d_in[8];
    const float* b2   = (const float*)d_in[9];

    const int N = in_sizes[0] / F_IN;   // 100000
    const int E = in_sizes[1] / 2;      // 1600000

    char* base = (char*)d_ws;
    auto carve = [&](size_t bytes) -> void* {
        void* p = (void*)base;
        base += (bytes + 255) & ~(size_t)255;
        return p;
    };
    float* h1     = (float*)carve((size_t)N * C1 * 4);
    float* h1f    = (float*)carve((size_t)N * C1 * 4);
    float* as1    = (float*)carve((size_t)N * H1 * 4);
    float* ad1    = (float*)carve((size_t)N * H1 * 4);
    float* h2     = (float*)carve((size_t)N * C2 * 4);
    float* as2    = (float*)carve((size_t)N * 4);
    float* ad2    = (float*)carve((size_t)N * 4);
    int*   deg    = (int*)carve((size_t)N * 4);
    int*   excl   = (int*)carve((size_t)N * 4);
    int*   rowptr = (int*)carve((size_t)(N + 1) * 4);
    int*   cursor = (int*)carve((size_t)N * 4);
    int*   esrc   = (int*)carve((size_t)E * 4);
    int*   bsum   = (int*)carve(256 * 4);
    int*   bsumo  = (int*)carve(256 * 4);

    const int NB = (N + 511) / 512;

    hipMemsetAsync(deg, 0, (size_t)N * 4, stream);

    count_kernel<<<(E + 255) / 256, 256, 0, stream>>>(ei, deg, E);
    scan1_kernel<<<NB, 512, 0, stream>>>(deg, excl, bsum, N);
    scan2_kernel<<<1, 256, 0, stream>>>(bsum, bsumo, NB);
    scan3_kernel<<<NB, 512, 0, stream>>>(excl, bsumo, rowptr, cursor, N, E);
    scatter_kernel<<<(E + 255) / 256, 256, 0, stream>>>(ei, cursor, esrc, E);

    gemm1_kernel<<<(N + 63) / 64, 256, 0, stream>>>(x, W1, as1w, ad1w, h1, as1, ad1, N);
    agg1_kernel<<<(N + 3) / 4, 256, 0, stream>>>(rowptr, esrc, h1, as1, ad1, b1, h1f, N);
    gemm2_kernel<<<N / 8, 320, 0, stream>>>(h1f, W2, as2w, ad2w, h2, as2, ad2, N);
    agg2_kernel<<<(N + 3) / 4, 256, 0, stream>>>(rowptr, esrc, h2, as2, ad2, b2,
                                                 (float*)d_out, N);
}